// Round 4
// baseline (623.752 us; speedup 1.0000x reference)
//
#include <hip/hip_runtime.h>
#include <hip/hip_bf16.h>

// LightGCN 3-hop GraphConv (M4_86749749444857).
// R9->R10: spmm geometry 4 rows/wave (16 lanes/row, ushort4) -> 8 rows/wave
// (8 lanes/row, ushort8). Gather instr count per edge halves; in-flight cache
// lines per wave 32 -> 64. Attacks the remaining latency-bound signature
// (3.8 TB/s L2-fetch, VALU 29%, occ 75% -- nothing saturated). Sort pipeline
// (512-row buckets, R9 fine) unchanged.

#define D 64
typedef unsigned short u16;

#define NBP   512    // padded bucket count (real NB = ceil(n/512) = 293)
#define BSH   9      // 512 rows/bucket
#define TILE  2048   // edges per coarse block
#define FCAP  4608   // fine LDS chunk slots (128 rows x 32 mean = 4096 + 8 sigma)

__device__ __forceinline__ float bf2f(u16 h) {
    union { unsigned int u; float f; } c;
    c.u = ((unsigned int)h) << 16;
    return c.f;
}
__device__ __forceinline__ u16 f2bf(float f) {
    union { float f; unsigned int u; } c; c.f = f;
    unsigned int r = c.u + 0x7FFFu + ((c.u >> 16) & 1u);  // RNE
    return (u16)(r >> 16);
}

struct U4 { u16 a, b, c, d; } __attribute__((aligned(8)));
struct U8 { u16 h0, h1, h2, h3, h4, h5, h6, h7; } __attribute__((aligned(16)));

// ---------------- dtype sniffing ----------------
__global__ void detect_kernel(const u16* __restrict__ emb,
                              const u16* __restrict__ vals,
                              int* __restrict__ flags) {
    int lane = threadIdx.x;  // 64 threads, 1 block
    int se = 0, sv = 0;
    for (int k = 0; k < 16; ++k) {
        int idx = (lane * 16 + k) * 2;
        u16 he = emb[idx];
        int ee = (he >> 7) & 0xFF;
        if (ee >= 100 && ee < 127) se++;
        u16 hv = vals[idx];
        int ev = (hv >> 7) & 0xFF;
        if ((hv >> 15) == 0 && ev >= 60 && ev < 123) sv++;
    }
    atomicAdd(&flags[0], se);
    atomicAdd(&flags[1], sv);
}

// ---------------- ego -> bf16 X0 ----------------
__global__ __launch_bounds__(256)
void convert_kernel(const void* __restrict__ ue, const void* __restrict__ ie,
                    const int* __restrict__ flags, u16* __restrict__ x0,
                    int total, int usz) {
    int i = (blockIdx.x * blockDim.x + threadIdx.x) * 4;
    if (i >= total) return;
    const void* src = (i < usz) ? ue : ie;
    int off = (i < usz) ? i : i - usz;
    U4 o;
    if (flags[0] >= 512) {
        o = *(const U4*)((const u16*)src + off);
    } else {
        const float4 v = *(const float4*)((const float*)src + off);
        o.a = f2bf(v.x); o.b = f2bf(v.y); o.c = f2bf(v.z); o.d = f2bf(v.w);
    }
    *(U4*)(x0 + i) = o;
}

// ---------------- bucket histogram (LDS-aggregated) ----------------
__global__ __launch_bounds__(256)
void bhist_kernel(const int* __restrict__ row, int* __restrict__ bcnt, int nnz) {
    __shared__ int h[NBP];
    int t = threadIdx.x;
    h[t] = 0; h[t + 256] = 0;
    __syncthreads();
    for (int i = blockIdx.x * 256 + t; i < nnz; i += gridDim.x * 256)
        atomicAdd(&h[row[i] >> BSH], 1);
    __syncthreads();
    if (h[t])       atomicAdd(&bcnt[t],       h[t]);
    if (h[t + 256]) atomicAdd(&bcnt[t + 256], h[t + 256]);
}

// single block, 512 threads: exclusive scan of bucket counts
__global__ void bscan_kernel(const int* __restrict__ bcnt, int* __restrict__ bbase,
                             int* __restrict__ bcursor, int nb, int nnz) {
    __shared__ int buf[NBP];
    int t = threadIdx.x;
    int v = (t < nb) ? bcnt[t] : 0;
    buf[t] = v;
    __syncthreads();
    for (int off = 1; off < NBP; off <<= 1) {
        int y = (t >= off) ? buf[t - off] : 0;
        __syncthreads();
        buf[t] += y;
        __syncthreads();
    }
    int excl = buf[t] - v;
    bbase[t] = excl;
    bcursor[t] = excl;
    if (t == 0) bbase[nb] = nnz;
}

// ---------------- coarse sort: COO -> bucket-grouped es2 ----------------
// es2 entry: .x = (row&511)<<18 | col   .y = val bits
__global__ __launch_bounds__(256)
void coarse_kernel(const int* __restrict__ row, const int* __restrict__ col,
                   const void* __restrict__ vals, const int* __restrict__ flags,
                   int* __restrict__ bcursor, int2* __restrict__ es2, int nnz) {
    __shared__ int2 ebuf[TILE];
    __shared__ u16  slotb[TILE];
    __shared__ int  hcnt[NBP], hscn[NBP], goff[NBP];
    int t = threadIdx.x;
    int base = blockIdx.x * TILE;
    int tcnt = nnz - base; if (tcnt > TILE) tcnt = TILE;
    bool vbf = (flags[1] >= 512);

    hcnt[t] = 0; hcnt[t + 256] = 0;
    __syncthreads();

    int eb[8], er[8], ep[8], ev[8];
#pragma unroll
    for (int k = 0; k < 8; ++k) {
        int i = base + k * 256 + t;
        eb[k] = -1;
        if (k * 256 + t < tcnt) {
            int r = row[i];
            int c = col[i];
            float v = vbf ? bf2f(((const u16*)vals)[i]) : ((const float*)vals)[i];
            eb[k] = r >> BSH;
            ep[k] = ((r & 511) << 18) | c;
            ev[k] = __float_as_int(v);
            er[k] = atomicAdd(&hcnt[eb[k]], 1);
        }
    }
    __syncthreads();
    hscn[t] = hcnt[t]; hscn[t + 256] = hcnt[t + 256];
    __syncthreads();
    for (int off = 1; off < NBP; off <<= 1) {
        int a0 = (t >= off) ? hscn[t - off] : 0;
        int a1 = (t + 256 >= off) ? hscn[t + 256 - off] : 0;
        __syncthreads();
        hscn[t] += a0; hscn[t + 256] += a1;
        __syncthreads();
    }
#pragma unroll
    for (int k = 0; k < 8; ++k) {
        if (eb[k] >= 0) {
            int slot = hscn[eb[k]] - hcnt[eb[k]] + er[k];
            ebuf[slot] = make_int2(ep[k], ev[k]);
            slotb[slot] = (u16)eb[k];
        }
    }
    __syncthreads();
    if (hcnt[t] > 0)       goff[t]       = atomicAdd(&bcursor[t],       hcnt[t]);
    if (hcnt[t + 256] > 0) goff[t + 256] = atomicAdd(&bcursor[t + 256], hcnt[t + 256]);
    __syncthreads();
#pragma unroll
    for (int k = 0; k < 8; ++k) {
        int p = k * 256 + t;
        if (p < tcnt) {
            int b = slotb[p];
            int dest = goff[b] + (p - (hscn[b] - hcnt[b]));
            es2[dest] = ebuf[p];
        }
    }
}

// ---------------- fine sort + rp emit: 1 block / 512-row bucket, 4 chunks ----
// Pass 1 (HBM): hist[512]. Scan once. Then per 128-row chunk: re-scan bucket
// (L2-hot), LDS-scatter chunk edges into obuf at sorted positions, stream
// obuf -> es coalesced. No scattered global writes.
__global__ __launch_bounds__(512)
void fine_kernel(const int2* __restrict__ es2, const int* __restrict__ bbase,
                 int2* __restrict__ es, int* __restrict__ rp, int n, int nnz) {
    __shared__ int2 obuf[FCAP];
    __shared__ int hist[512], scn[512], cur[128];
    int b = blockIdx.x, t = threadIdx.x;  // 512 threads
    int r0 = b << BSH;
    int s = bbase[b], e = bbase[b + 1];
    if (b == 0 && t == 0) rp[n] = nnz;

    hist[t] = 0;
    __syncthreads();
    for (int i = s + t; i < e; i += 512)
        atomicAdd(&hist[(unsigned)es2[i].x >> 18], 1);
    __syncthreads();
    scn[t] = hist[t];
    __syncthreads();
    for (int off = 1; off < 512; off <<= 1) {
        int a = (t >= off) ? scn[t - off] : 0;
        __syncthreads();
        scn[t] += a;
        __syncthreads();
    }
    {
        int ex = scn[t] - hist[t];
        int r = r0 + t;
        if (r < n) rp[r] = s + ex;
    }

    for (int c = 0; c < 4; ++c) {
        int qb = c * 128;
        int q0 = qb ? scn[qb - 1] : 0;           // excl prefix at chunk start
        int qcnt = scn[qb + 127] - q0;
        int ds = s + q0;
        bool fit = (qcnt <= FCAP);
        if (t < 128) {
            int ex = scn[qb + t] - hist[qb + t];
            cur[t] = fit ? (ex - q0) : (s + ex);  // LDS slot vs global dest
        }
        __syncthreads();
        if (fit) {
            for (int i = s + t; i < e; i += 512) {
                int2 p = es2[i];
                int rl = (unsigned)p.x >> 18;
                if ((rl >> 7) == c) {
                    int pos = atomicAdd(&cur[rl & 127], 1);
                    obuf[pos] = make_int2(p.x & 0x3FFFF, p.y);
                }
            }
            __syncthreads();
            for (int p2 = t; p2 < qcnt; p2 += 512)
                es[ds + p2] = obuf[p2];
            __syncthreads();
        } else {
            // statistically-unreachable overflow: direct global scatter
            for (int i = s + t; i < e; i += 512) {
                int2 p = es2[i];
                int rl = (unsigned)p.x >> 18;
                if ((rl >> 7) == c) {
                    int pos = atomicAdd(&cur[rl & 127], 1);
                    es[pos] = make_int2(p.x & 0x3FFFF, p.y);
                }
            }
            __syncthreads();
        }
    }
}

// ---------------- SpMM: 8 rows/wave, 8 lanes/row, ushort8 gather ----------------
// Lane l: octet oct = l>>3 owns row (wid*8 + oct); sub = l&7 owns dims 8*sub..8*sub+7.
// Per unroll-step one gather instruction moves 8x128B lines (one per octet);
// with the x8 edge unroll a wave keeps 64 lines in flight.

#define ACC8(A, w, v) { \
    A##0 += (w) * bf2f((v).h0); A##1 += (w) * bf2f((v).h1); \
    A##2 += (w) * bf2f((v).h2); A##3 += (w) * bf2f((v).h3); \
    A##4 += (w) * bf2f((v).h4); A##5 += (w) * bf2f((v).h5); \
    A##6 += (w) * bf2f((v).h6); A##7 += (w) * bf2f((v).h7); }

__global__ __launch_bounds__(256)
void spmm_kernel(const u16* __restrict__ x, u16* __restrict__ y,
                 const int* __restrict__ rp, const int2* __restrict__ es, int n) {
    int wid  = (blockIdx.x * blockDim.x + threadIdx.x) >> 6;
    int lane = threadIdx.x & 63;
    int oct  = lane >> 3;
    int sub  = lane & 7;
    int r    = (wid << 3) + oct;
    int e = 0, e1 = 0;
    if (r < n) { e = rp[r]; e1 = rp[r + 1]; }
    const u16* xs = x + (sub << 3);

    float a0 = 0.f, a1 = 0.f, a2 = 0.f, a3 = 0.f, a4 = 0.f, a5 = 0.f, a6 = 0.f, a7 = 0.f;
    float b0 = 0.f, b1 = 0.f, b2 = 0.f, b3 = 0.f, b4 = 0.f, b5 = 0.f, b6 = 0.f, b7 = 0.f;

    for (; e + 8 <= e1; e += 8) {
        int2 p0 = es[e],     p1 = es[e + 1], p2 = es[e + 2], p3 = es[e + 3];
        int2 p4 = es[e + 4], p5 = es[e + 5], p6 = es[e + 6], p7 = es[e + 7];
        U8 v0 = *(const U8*)(xs + (p0.x << 6));
        U8 v1 = *(const U8*)(xs + (p1.x << 6));
        U8 v2 = *(const U8*)(xs + (p2.x << 6));
        U8 v3 = *(const U8*)(xs + (p3.x << 6));
        U8 v4 = *(const U8*)(xs + (p4.x << 6));
        U8 v5 = *(const U8*)(xs + (p5.x << 6));
        U8 v6 = *(const U8*)(xs + (p6.x << 6));
        U8 v7 = *(const U8*)(xs + (p7.x << 6));
        float w0 = __int_as_float(p0.y), w1 = __int_as_float(p1.y);
        float w2 = __int_as_float(p2.y), w3 = __int_as_float(p3.y);
        float w4 = __int_as_float(p4.y), w5 = __int_as_float(p5.y);
        float w6 = __int_as_float(p6.y), w7 = __int_as_float(p7.y);
        ACC8(a, w0, v0); ACC8(b, w1, v1);
        ACC8(a, w2, v2); ACC8(b, w3, v3);
        ACC8(a, w4, v4); ACC8(b, w5, v5);
        ACC8(a, w6, v6); ACC8(b, w7, v7);
    }
    for (; e < e1; ++e) {
        int2 p = es[e];
        U8 v = *(const U8*)(xs + (p.x << 6));
        float w = __int_as_float(p.y);
        ACC8(a, w, v);
    }
    if (r < n) {
        U8 o;
        o.h0 = f2bf(a0 + b0); o.h1 = f2bf(a1 + b1);
        o.h2 = f2bf(a2 + b2); o.h3 = f2bf(a3 + b3);
        o.h4 = f2bf(a4 + b4); o.h5 = f2bf(a5 + b5);
        o.h6 = f2bf(a6 + b6); o.h7 = f2bf(a7 + b7);
        *(U8*)(y + (r << 6) + (sub << 3)) = o;
    }
}

__global__ __launch_bounds__(256)
void spmm_last_kernel(const u16* __restrict__ x2, const u16* __restrict__ x1,
                      float* __restrict__ out,
                      const int* __restrict__ rp, const int2* __restrict__ es, int n) {
    int wid  = (blockIdx.x * blockDim.x + threadIdx.x) >> 6;
    int lane = threadIdx.x & 63;
    int oct  = lane >> 3;
    int sub  = lane & 7;
    int r    = (wid << 3) + oct;
    int e = 0, e1 = 0;
    if (r < n) { e = rp[r]; e1 = rp[r + 1]; }
    const u16* xs = x2 + (sub << 3);

    float a0 = 0.f, a1 = 0.f, a2 = 0.f, a3 = 0.f, a4 = 0.f, a5 = 0.f, a6 = 0.f, a7 = 0.f;
    float b0 = 0.f, b1 = 0.f, b2 = 0.f, b3 = 0.f, b4 = 0.f, b5 = 0.f, b6 = 0.f, b7 = 0.f;

    for (; e + 8 <= e1; e += 8) {
        int2 p0 = es[e],     p1 = es[e + 1], p2 = es[e + 2], p3 = es[e + 3];
        int2 p4 = es[e + 4], p5 = es[e + 5], p6 = es[e + 6], p7 = es[e + 7];
        U8 v0 = *(const U8*)(xs + (p0.x << 6));
        U8 v1 = *(const U8*)(xs + (p1.x << 6));
        U8 v2 = *(const U8*)(xs + (p2.x << 6));
        U8 v3 = *(const U8*)(xs + (p3.x << 6));
        U8 v4 = *(const U8*)(xs + (p4.x << 6));
        U8 v5 = *(const U8*)(xs + (p5.x << 6));
        U8 v6 = *(const U8*)(xs + (p6.x << 6));
        U8 v7 = *(const U8*)(xs + (p7.x << 6));
        float w0 = __int_as_float(p0.y), w1 = __int_as_float(p1.y);
        float w2 = __int_as_float(p2.y), w3 = __int_as_float(p3.y);
        float w4 = __int_as_float(p4.y), w5 = __int_as_float(p5.y);
        float w6 = __int_as_float(p6.y), w7 = __int_as_float(p7.y);
        ACC8(a, w0, v0); ACC8(b, w1, v1);
        ACC8(a, w2, v2); ACC8(b, w3, v3);
        ACC8(a, w4, v4); ACC8(b, w5, v5);
        ACC8(a, w6, v6); ACC8(b, w7, v7);
    }
    for (; e < e1; ++e) {
        int2 p = es[e];
        U8 v = *(const U8*)(xs + (p.x << 6));
        float w = __int_as_float(p.y);
        ACC8(a, w, v);
    }
    if (r < n) {
        int idx = (r << 6) + (sub << 3);
        U8 h1v = *(const U8*)(x1 + idx);
        U8 h2v = *(const U8*)(x2 + idx);
        float4 o0, o1;
        o0.x = (bf2f(h1v.h0) + bf2f(h2v.h0) + (a0 + b0)) * (1.0f / 3.0f);
        o0.y = (bf2f(h1v.h1) + bf2f(h2v.h1) + (a1 + b1)) * (1.0f / 3.0f);
        o0.z = (bf2f(h1v.h2) + bf2f(h2v.h2) + (a2 + b2)) * (1.0f / 3.0f);
        o0.w = (bf2f(h1v.h3) + bf2f(h2v.h3) + (a3 + b3)) * (1.0f / 3.0f);
        o1.x = (bf2f(h1v.h4) + bf2f(h2v.h4) + (a4 + b4)) * (1.0f / 3.0f);
        o1.y = (bf2f(h1v.h5) + bf2f(h2v.h5) + (a5 + b5)) * (1.0f / 3.0f);
        o1.z = (bf2f(h1v.h6) + bf2f(h2v.h6) + (a6 + b6)) * (1.0f / 3.0f);
        o1.w = (bf2f(h1v.h7) + bf2f(h2v.h7) + (a7 + b7)) * (1.0f / 3.0f);
        *(float4*)(out + idx) = o0;
        *(float4*)(out + idx + 4) = o1;
        float4 l0, l1;
        l0.x = bf2f(h1v.h0); l0.y = bf2f(h1v.h1); l0.z = bf2f(h1v.h2); l0.w = bf2f(h1v.h3);
        l1.x = bf2f(h1v.h4); l1.y = bf2f(h1v.h5); l1.z = bf2f(h1v.h6); l1.w = bf2f(h1v.h7);
        *(float4*)(out + (size_t)n * D + idx) = l0;
        *(float4*)(out + (size_t)n * D + idx + 4) = l1;
    }
}

// ---------------- launch ----------------

extern "C" void kernel_launch(void* const* d_in, const int* in_sizes, int n_in,
                              void* d_out, int out_size, void* d_ws, size_t ws_size,
                              hipStream_t stream) {
    const void* ue   = d_in[0];
    const void* ie   = d_in[1];
    const int*  row  = (const int*)d_in[2];
    const int*  col  = (const int*)d_in[3];
    const void* vals = d_in[4];

    const int nu  = in_sizes[0] / D;   // 100000
    const int ni  = in_sizes[1] / D;   //  50000
    const int n   = nu + ni;           // 150000
    const int nnz = in_sizes[2];       // 4800000

    // workspace (~97 MB). es2 aliases X1+X2 (dead before spmm writes X1).
    char* ws = (char*)d_ws;
    u16*  X0     = (u16*)ws;   ws += (size_t)n * D * sizeof(u16);
    u16*  X1     = (u16*)ws;   ws += (size_t)n * D * sizeof(u16);
    u16*  X2     = (u16*)ws;   ws += (size_t)n * D * sizeof(u16);
    int2* es2    = (int2*)X1;  // nnz*8B == 2*n*D*2B exactly
    int2* es     = (int2*)ws;  ws += (size_t)nnz * sizeof(int2);
    int*  rp     = (int*)ws;   ws += (size_t)(n + 1) * sizeof(int);
    int*  bcnt   = (int*)ws;   ws += NBP * sizeof(int);
    int*  flags  = (int*)ws;   ws += 2 * sizeof(int);
    int*  bbase  = (int*)ws;   ws += (NBP + 1) * sizeof(int);
    int*  bcursor= (int*)ws;   ws += NBP * sizeof(int);

    const int tb = 256;
    const int rblocks = (n + 31) / 32;             // 8 rows/wave, 4 waves/block
    const int cblocks = (n * D / 4 + tb - 1) / tb;
    const int NB      = (n + 511) / 512;            // 293
    const int coarseb = (nnz + TILE - 1) / TILE;    // 2344

    // zero bcnt + flags (contiguous)
    hipMemsetAsync(bcnt, 0, (NBP + 2) * sizeof(int), stream);
    detect_kernel <<<1, 64, 0, stream>>>((const u16*)ue, (const u16*)vals, flags);
    convert_kernel<<<cblocks, tb, 0, stream>>>(ue, ie, flags, X0, n * D, nu * D);
    bhist_kernel  <<<512, tb, 0, stream>>>(row, bcnt, nnz);
    bscan_kernel  <<<1, NBP, 0, stream>>>(bcnt, bbase, bcursor, NB, nnz);
    coarse_kernel <<<coarseb, tb, 0, stream>>>(row, col, vals, flags, bcursor, es2, nnz);
    fine_kernel   <<<NB, 512, 0, stream>>>(es2, bbase, es, rp, n, nnz);

    spmm_kernel     <<<rblocks, tb, 0, stream>>>(X0, X1, rp, es, n);
    spmm_kernel     <<<rblocks, tb, 0, stream>>>(X1, X2, rp, es, n);
    spmm_last_kernel<<<rblocks, tb, 0, stream>>>(X2, X1, (float*)d_out, rp, es, n);
}